// Round 3
// baseline (6405.974 us; speedup 1.0000x reference)
//
#include <hip/hip_runtime.h>
#include <math.h>

#define NODES 81
#define B_SZ 512
#define T_STEPS 12
#define NSEQ (B_SZ * NODES)   // 41472
#define HID 128
#define GATES 512
#define G 32                  // sequences per block
#define HPAD 34               // padded row stride for hT (8B aligned, conflict-free)

// ---------------------------------------------------------------------------
// Prep: gate-permuted (j' = unit*4 + type), k-major weights [128][512].
// ---------------------------------------------------------------------------
__global__ void prep_kernel(const float* __restrict__ Whh0,
                            const float* __restrict__ Wih1,
                            const float* __restrict__ Whh1,
                            const float* __restrict__ Wih0,
                            const float* __restrict__ bih0, const float* __restrict__ bhh0,
                            const float* __restrict__ bih1, const float* __restrict__ bhh1,
                            float* __restrict__ WT0,
                            float* __restrict__ WT1i,
                            float* __restrict__ WT1h,
                            float* __restrict__ wih0p,
                            float* __restrict__ b0p,
                            float* __restrict__ b1p)
{
    int idx = blockIdx.x * 256 + threadIdx.x;   // 198144 total, exact
    if (idx < 65536) {
        int k = idx >> 9, jp = idx & 511;
        int kh = jp >> 2, ty = jp & 3;
        WT0[idx] = Whh0[(ty * 128 + kh) * 128 + k];
    } else if (idx < 131072) {
        int r = idx - 65536;
        int k = r >> 9, jp = r & 511;
        int kh = jp >> 2, ty = jp & 3;
        WT1i[r] = Wih1[(ty * 128 + kh) * 128 + k];
    } else if (idx < 196608) {
        int r = idx - 131072;
        int k = r >> 9, jp = r & 511;
        int kh = jp >> 2, ty = jp & 3;
        WT1h[r] = Whh1[(ty * 128 + kh) * 128 + k];
    } else if (idx < 197120) {
        int jp = idx - 196608;
        int kh = jp >> 2, ty = jp & 3;
        wih0p[jp] = Wih0[ty * 128 + kh];
    } else if (idx < 197632) {
        int jp = idx - 197120;
        int kh = jp >> 2, ty = jp & 3;
        int j = ty * 128 + kh;
        b0p[jp] = bih0[j] + bhh0[j];
    } else if (idx < 198144) {
        int jp = idx - 197632;
        int kh = jp >> 2, ty = jp & 3;
        int j = ty * 128 + kh;
        b1p[jp] = bih1[j] + bhh1[j];
    }
}

// ---------------------------------------------------------------------------
// income = einsum('bta,an->bnt'); stored t-major: x[t][seq], seq = b*81+n
// ---------------------------------------------------------------------------
__global__ void income_kernel(const float* __restrict__ g_data,
                              const float* __restrict__ w,
                              float* __restrict__ x)
{
    int idx = blockIdx.x * 256 + threadIdx.x;   // 497664 exactly
    int n = idx % NODES;
    int r = idx / NODES;
    int t = r % T_STEPS;
    int b = r / T_STEPS;
    const float* grow = g_data + (b * T_STEPS + t) * NODES;
    float s = 0.f;
    #pragma unroll 3
    for (int a = 0; a < NODES; ++a)
        s += grow[a] * w[a * NODES + n];
    x[t * NSEQ + b * NODES + n] = s;
}

__device__ __forceinline__ float sigf(float v) { return 1.f / (1.f + expf(-v)); }

// 16 FMAs of one h-scalar against 4 weight float4s into acc half S (S=0/1)
#define ROW16(S, HS, W0, W1, W2, W3) \
    a[(S)*16+ 0] += (HS)*(W0).x; a[(S)*16+ 1] += (HS)*(W0).y; a[(S)*16+ 2] += (HS)*(W0).z; a[(S)*16+ 3] += (HS)*(W0).w; \
    a[(S)*16+ 4] += (HS)*(W1).x; a[(S)*16+ 5] += (HS)*(W1).y; a[(S)*16+ 6] += (HS)*(W1).z; a[(S)*16+ 7] += (HS)*(W1).w; \
    a[(S)*16+ 8] += (HS)*(W2).x; a[(S)*16+ 9] += (HS)*(W2).y; a[(S)*16+10] += (HS)*(W2).z; a[(S)*16+11] += (HS)*(W2).w; \
    a[(S)*16+12] += (HS)*(W3).x; a[(S)*16+13] += (HS)*(W3).y; a[(S)*16+14] += (HS)*(W3).z; a[(S)*16+15] += (HS)*(W3).w;

// init acc half S with x*wi + b  (weights W0..3, biases Bv0..3 as float4 values)
#define INIT16(S, XS) \
    a[(S)*16+ 0] = (XS)*w0.x + bv0.x; a[(S)*16+ 1] = (XS)*w0.y + bv0.y; \
    a[(S)*16+ 2] = (XS)*w0.z + bv0.z; a[(S)*16+ 3] = (XS)*w0.w + bv0.w; \
    a[(S)*16+ 4] = (XS)*w1.x + bv1.x; a[(S)*16+ 5] = (XS)*w1.y + bv1.y; \
    a[(S)*16+ 6] = (XS)*w1.z + bv1.z; a[(S)*16+ 7] = (XS)*w1.w + bv1.w; \
    a[(S)*16+ 8] = (XS)*w2.x + bv2.x; a[(S)*16+ 9] = (XS)*w2.y + bv2.y; \
    a[(S)*16+10] = (XS)*w2.z + bv2.z; a[(S)*16+11] = (XS)*w2.w + bv2.w; \
    a[(S)*16+12] = (XS)*w3.x + bv3.x; a[(S)*16+13] = (XS)*w3.y + bv3.y; \
    a[(S)*16+14] = (XS)*w3.z + bv3.z; a[(S)*16+15] = (XS)*w3.w + bv3.w;

// ---------------------------------------------------------------------------
// Fused 2-layer LSTM + FC head. Block = 512 threads = 32 jg x 16 sg.
// Thread (jg, sg): 2 seqs (sg*2..+2) x 4 hidden units (jg*4..+4) x 4 gates.
// h state transposed in LDS: hT[k][seq], stride HPAD.
// ---------------------------------------------------------------------------
__global__ __launch_bounds__(512)
__attribute__((amdgpu_waves_per_eu(4, 4)))
void lstm_main(
    const float* __restrict__ x,       // [12][NSEQ]
    const float* __restrict__ WT0,     // [128][512]
    const float* __restrict__ WT1i,    // [128][512]
    const float* __restrict__ WT1h,    // [128][512]
    const float* __restrict__ wih0p,   // [512]
    const float* __restrict__ b0p,     // [512]
    const float* __restrict__ b1p,     // [512]
    const float* __restrict__ fc1_w,   // [32][128]
    const float* __restrict__ fc1_b,   // [32]
    const float* __restrict__ fc2_w,   // [32]
    const float* __restrict__ fc2_b,   // [1]
    float* __restrict__ out)           // [NSEQ]
{
    __shared__ float hT0[HID * HPAD];
    __shared__ float hT1[HID * HPAD];

    const int tid = threadIdx.x;
    const int sg = tid & 15;           // 0..15 -> seqs sg*2, sg*2+1
    const int jg = tid >> 4;           // 0..31 -> units jg*4..+4
    const int sg2 = sg * 2;
    const int jbase = jg * 16;
    const int seq0 = blockIdx.x * G;

    for (int i = tid; i < HID * HPAD; i += 512) { hT0[i] = 0.f; hT1[i] = 0.f; }

    float c0[8], c1[8];                // [s*4+u]
    #pragma unroll
    for (int i = 0; i < 8; ++i) { c0[i] = 0.f; c1[i] = 0.f; }
    __syncthreads();

    float a[32];                       // acc [s*16 + u*4 + type]
    float hn[8];                       // [s*4+u]

    for (int t = 0; t < T_STEPS; ++t) {
        // ===== layer 0 matmul: a = x*wih0' + b0 + h0 @ WT0 =====
        {
            float2 xv = *(const float2*)&x[t * NSEQ + seq0 + sg2];
            float4 w0 = *(const float4*)(wih0p + jbase + 0);
            float4 w1 = *(const float4*)(wih0p + jbase + 4);
            float4 w2 = *(const float4*)(wih0p + jbase + 8);
            float4 w3 = *(const float4*)(wih0p + jbase + 12);
            float4 bv0 = *(const float4*)(b0p + jbase + 0);
            float4 bv1 = *(const float4*)(b0p + jbase + 4);
            float4 bv2 = *(const float4*)(b0p + jbase + 8);
            float4 bv3 = *(const float4*)(b0p + jbase + 12);
            INIT16(0, xv.x)
            INIT16(1, xv.y)
        }
        #pragma unroll 2
        for (int k = 0; k < HID; ++k) {
            float2 h2 = *(const float2*)&hT0[k * HPAD + sg2];
            const float* wr = WT0 + k * GATES + jbase;
            float4 w0 = *(const float4*)(wr + 0);
            float4 w1 = *(const float4*)(wr + 4);
            float4 w2 = *(const float4*)(wr + 8);
            float4 w3 = *(const float4*)(wr + 12);
            ROW16(0, h2.x, w0, w1, w2, w3)
            ROW16(1, h2.y, w0, w1, w2, w3)
        }
        // ===== layer 0 update (pure registers) =====
        #pragma unroll
        for (int s = 0; s < 2; ++s)
            #pragma unroll
            for (int u = 0; u < 4; ++u) {
                float iv = sigf(a[s*16+u*4+0]);
                float fv = sigf(a[s*16+u*4+1]);
                float gv = tanhf(a[s*16+u*4+2]);
                float ov = sigf(a[s*16+u*4+3]);
                float c = fv * c0[s*4+u] + iv * gv;
                c0[s*4+u] = c;
                hn[s*4+u] = ov * tanhf(c);
            }
        __syncthreads();               // all reads of hT0 done
        #pragma unroll
        for (int u = 0; u < 4; ++u)
            *(float2*)&hT0[(jg*4+u) * HPAD + sg2] = make_float2(hn[u], hn[4+u]);
        __syncthreads();               // new h0 visible

        // ===== layer 1 matmul: a = b1 + h0 @ WT1i + h1 @ WT1h =====
        {
            float4 bv0 = *(const float4*)(b1p + jbase + 0);
            float4 bv1 = *(const float4*)(b1p + jbase + 4);
            float4 bv2 = *(const float4*)(b1p + jbase + 8);
            float4 bv3 = *(const float4*)(b1p + jbase + 12);
            a[0]=bv0.x; a[1]=bv0.y; a[2]=bv0.z; a[3]=bv0.w;
            a[4]=bv1.x; a[5]=bv1.y; a[6]=bv1.z; a[7]=bv1.w;
            a[8]=bv2.x; a[9]=bv2.y; a[10]=bv2.z; a[11]=bv2.w;
            a[12]=bv3.x; a[13]=bv3.y; a[14]=bv3.z; a[15]=bv3.w;
            a[16]=bv0.x; a[17]=bv0.y; a[18]=bv0.z; a[19]=bv0.w;
            a[20]=bv1.x; a[21]=bv1.y; a[22]=bv1.z; a[23]=bv1.w;
            a[24]=bv2.x; a[25]=bv2.y; a[26]=bv2.z; a[27]=bv2.w;
            a[28]=bv3.x; a[29]=bv3.y; a[30]=bv3.z; a[31]=bv3.w;
        }
        #pragma unroll 2
        for (int k = 0; k < HID; ++k) {
            float2 h02 = *(const float2*)&hT0[k * HPAD + sg2];
            const float* wri = WT1i + k * GATES + jbase;
            float4 w0 = *(const float4*)(wri + 0);
            float4 w1 = *(const float4*)(wri + 4);
            float4 w2 = *(const float4*)(wri + 8);
            float4 w3 = *(const float4*)(wri + 12);
            ROW16(0, h02.x, w0, w1, w2, w3)
            ROW16(1, h02.y, w0, w1, w2, w3)
            float2 h12 = *(const float2*)&hT1[k * HPAD + sg2];
            const float* wrh = WT1h + k * GATES + jbase;
            float4 v0 = *(const float4*)(wrh + 0);
            float4 v1 = *(const float4*)(wrh + 4);
            float4 v2 = *(const float4*)(wrh + 8);
            float4 v3 = *(const float4*)(wrh + 12);
            ROW16(0, h12.x, v0, v1, v2, v3)
            ROW16(1, h12.y, v0, v1, v2, v3)
        }
        // ===== layer 1 update =====
        #pragma unroll
        for (int s = 0; s < 2; ++s)
            #pragma unroll
            for (int u = 0; u < 4; ++u) {
                float iv = sigf(a[s*16+u*4+0]);
                float fv = sigf(a[s*16+u*4+1]);
                float gv = tanhf(a[s*16+u*4+2]);
                float ov = sigf(a[s*16+u*4+3]);
                float c = fv * c1[s*4+u] + iv * gv;
                c1[s*4+u] = c;
                hn[s*4+u] = ov * tanhf(c);
            }
        __syncthreads();               // all reads of hT1 done
        #pragma unroll
        for (int u = 0; u < 4; ++u)
            *(float2*)&hT1[(jg*4+u) * HPAD + sg2] = make_float2(hn[u], hn[4+u]);
        __syncthreads();               // new h1 visible (also protects next L0 h0 write)
    }

    // ===== FC head =====
    float hidv[2];
    #pragma unroll
    for (int r = 0; r < 2; ++r) {
        int task = tid + r * 512;      // 0..1023 = 32 seq x 32 j
        int sL = task & 31, j = task >> 5;
        float ssum = fc1_b[j];
        const float* wrow = fc1_w + j * HID;
        #pragma unroll 8
        for (int k = 0; k < HID; ++k) ssum += hT1[k * HPAD + sL] * wrow[k];
        hidv[r] = fmaxf(ssum, 0.f);
    }
    __syncthreads();
    #pragma unroll
    for (int r = 0; r < 2; ++r) {
        int task = tid + r * 512;
        hT0[(task & 31) * HPAD + (task >> 5)] = hidv[r];   // hid[seq][j]
    }
    __syncthreads();
    if (tid < G) {
        float ssum = fc2_b[0];
        #pragma unroll
        for (int j = 0; j < 32; ++j) ssum += hT0[tid * HPAD + j] * fc2_w[j];
        out[seq0 + tid] = fmaxf(ssum, 0.f);
    }
}

// ---------------------------------------------------------------------------
extern "C" void kernel_launch(void* const* d_in, const int* in_sizes, int n_in,
                              void* d_out, int out_size, void* d_ws, size_t ws_size,
                              hipStream_t stream)
{
    const float* g_data = (const float*)d_in[0];
    const float* weights = (const float*)d_in[1];
    const float* Wih0   = (const float*)d_in[2];
    const float* Whh0   = (const float*)d_in[3];
    const float* bih0   = (const float*)d_in[4];
    const float* bhh0   = (const float*)d_in[5];
    const float* Wih1   = (const float*)d_in[6];
    const float* Whh1   = (const float*)d_in[7];
    const float* bih1   = (const float*)d_in[8];
    const float* bhh1   = (const float*)d_in[9];
    const float* fc1_w  = (const float*)d_in[10];
    const float* fc1_b  = (const float*)d_in[11];
    const float* fc2_w  = (const float*)d_in[12];
    const float* fc2_b  = (const float*)d_in[13];
    float* out = (float*)d_out;

    float* ws     = (float*)d_ws;
    float* x      = ws;                  // 497664
    float* WT0    = x + NSEQ * T_STEPS;  // 65536
    float* WT1i   = WT0 + 65536;         // 65536
    float* WT1h   = WT1i + 65536;        // 65536
    float* wih0p  = WT1h + 65536;        // 512
    float* b0p    = wih0p + 512;         // 512
    float* b1p    = b0p + 512;           // 512

    prep_kernel<<<774, 256, 0, stream>>>(Whh0, Wih1, Whh1, Wih0, bih0, bhh0, bih1, bhh1,
                                         WT0, WT1i, WT1h, wih0p, b0p, b1p);
    income_kernel<<<1944, 256, 0, stream>>>(g_data, weights, x);
    lstm_main<<<NSEQ / G, 512, 0, stream>>>(x, WT0, WT1i, WT1h, wih0p, b0p, b1p,
                                            fc1_w, fc1_b, fc2_w, fc2_b, out);
}

// Round 4
// 3729.996 us; speedup vs baseline: 1.7174x; 1.7174x over previous
//
#include <hip/hip_runtime.h>
#include <math.h>

#define NODES 81
#define B_SZ 512
#define T_STEPS 12
#define NSEQ (B_SZ * NODES)   // 41472
#define HID 128
#define GATES 512
#define G 32                  // sequences per block
#define HPAD 36               // padded row stride for hT (16B aligned, conflict-free)

// ---------------------------------------------------------------------------
// Prep: gate-permuted (j' = unit*4 + type), k-major weights [128][512].
// ---------------------------------------------------------------------------
__global__ void prep_kernel(const float* __restrict__ Whh0,
                            const float* __restrict__ Wih1,
                            const float* __restrict__ Whh1,
                            const float* __restrict__ Wih0,
                            const float* __restrict__ bih0, const float* __restrict__ bhh0,
                            const float* __restrict__ bih1, const float* __restrict__ bhh1,
                            float* __restrict__ WT0,
                            float* __restrict__ WT1i,
                            float* __restrict__ WT1h,
                            float* __restrict__ wih0p,
                            float* __restrict__ b0p,
                            float* __restrict__ b1p)
{
    int idx = blockIdx.x * 256 + threadIdx.x;   // 198144 total, exact
    if (idx < 65536) {
        int k = idx >> 9, jp = idx & 511;
        int kh = jp >> 2, ty = jp & 3;
        WT0[idx] = Whh0[(ty * 128 + kh) * 128 + k];
    } else if (idx < 131072) {
        int r = idx - 65536;
        int k = r >> 9, jp = r & 511;
        int kh = jp >> 2, ty = jp & 3;
        WT1i[r] = Wih1[(ty * 128 + kh) * 128 + k];
    } else if (idx < 196608) {
        int r = idx - 131072;
        int k = r >> 9, jp = r & 511;
        int kh = jp >> 2, ty = jp & 3;
        WT1h[r] = Whh1[(ty * 128 + kh) * 128 + k];
    } else if (idx < 197120) {
        int jp = idx - 196608;
        int kh = jp >> 2, ty = jp & 3;
        wih0p[jp] = Wih0[ty * 128 + kh];
    } else if (idx < 197632) {
        int jp = idx - 197120;
        int kh = jp >> 2, ty = jp & 3;
        int j = ty * 128 + kh;
        b0p[jp] = bih0[j] + bhh0[j];
    } else if (idx < 198144) {
        int jp = idx - 197632;
        int kh = jp >> 2, ty = jp & 3;
        int j = ty * 128 + kh;
        b1p[jp] = bih1[j] + bhh1[j];
    }
}

// ---------------------------------------------------------------------------
// income = einsum('bta,an->bnt'); stored t-major: x[t][seq], seq = b*81+n
// ---------------------------------------------------------------------------
__global__ void income_kernel(const float* __restrict__ g_data,
                              const float* __restrict__ w,
                              float* __restrict__ x)
{
    int idx = blockIdx.x * 256 + threadIdx.x;   // 497664 exactly
    int n = idx % NODES;
    int r = idx / NODES;
    int t = r % T_STEPS;
    int b = r / T_STEPS;
    const float* grow = g_data + (b * T_STEPS + t) * NODES;
    float s = 0.f;
    #pragma unroll 3
    for (int a = 0; a < NODES; ++a)
        s += grow[a] * w[a * NODES + n];
    x[t * NSEQ + b * NODES + n] = s;
}

__device__ __forceinline__ float sigf(float v) { return 1.f / (1.f + expf(-v)); }

// 16 FMAs of one h-scalar against 4 weight float4s into acc quarter S (0..3)
#define ROW16(S, HS, W0, W1, W2, W3) \
    a[(S)*16+ 0] += (HS)*(W0).x; a[(S)*16+ 1] += (HS)*(W0).y; a[(S)*16+ 2] += (HS)*(W0).z; a[(S)*16+ 3] += (HS)*(W0).w; \
    a[(S)*16+ 4] += (HS)*(W1).x; a[(S)*16+ 5] += (HS)*(W1).y; a[(S)*16+ 6] += (HS)*(W1).z; a[(S)*16+ 7] += (HS)*(W1).w; \
    a[(S)*16+ 8] += (HS)*(W2).x; a[(S)*16+ 9] += (HS)*(W2).y; a[(S)*16+10] += (HS)*(W2).z; a[(S)*16+11] += (HS)*(W2).w; \
    a[(S)*16+12] += (HS)*(W3).x; a[(S)*16+13] += (HS)*(W3).y; a[(S)*16+14] += (HS)*(W3).z; a[(S)*16+15] += (HS)*(W3).w;

// init acc quarter S with x*w + b (w0..3 / bv0..3 in scope as float4 values)
#define INIT16(S, XS) \
    a[(S)*16+ 0] = (XS)*w0.x + bv0.x; a[(S)*16+ 1] = (XS)*w0.y + bv0.y; \
    a[(S)*16+ 2] = (XS)*w0.z + bv0.z; a[(S)*16+ 3] = (XS)*w0.w + bv0.w; \
    a[(S)*16+ 4] = (XS)*w1.x + bv1.x; a[(S)*16+ 5] = (XS)*w1.y + bv1.y; \
    a[(S)*16+ 6] = (XS)*w1.z + bv1.z; a[(S)*16+ 7] = (XS)*w1.w + bv1.w; \
    a[(S)*16+ 8] = (XS)*w2.x + bv2.x; a[(S)*16+ 9] = (XS)*w2.y + bv2.y; \
    a[(S)*16+10] = (XS)*w2.z + bv2.z; a[(S)*16+11] = (XS)*w2.w + bv2.w; \
    a[(S)*16+12] = (XS)*w3.x + bv3.x; a[(S)*16+13] = (XS)*w3.y + bv3.y; \
    a[(S)*16+14] = (XS)*w3.z + bv3.z; a[(S)*16+15] = (XS)*w3.w + bv3.w;

// set acc quarter S to biases
#define INITB16(S) \
    a[(S)*16+ 0] = bv0.x; a[(S)*16+ 1] = bv0.y; a[(S)*16+ 2] = bv0.z; a[(S)*16+ 3] = bv0.w; \
    a[(S)*16+ 4] = bv1.x; a[(S)*16+ 5] = bv1.y; a[(S)*16+ 6] = bv1.z; a[(S)*16+ 7] = bv1.w; \
    a[(S)*16+ 8] = bv2.x; a[(S)*16+ 9] = bv2.y; a[(S)*16+10] = bv2.z; a[(S)*16+11] = bv2.w; \
    a[(S)*16+12] = bv3.x; a[(S)*16+13] = bv3.y; a[(S)*16+14] = bv3.z; a[(S)*16+15] = bv3.w;

// ---------------------------------------------------------------------------
// Fused 2-layer LSTM + FC head. Block = 256 threads = 32 jg x 8 sg.
// Thread (jg, sg): 4 seqs (sg*4..+4) x 4 hidden units (jg*4..+4) x 4 gates.
// h state transposed in LDS: hT[k][seq], stride HPAD.
// ---------------------------------------------------------------------------
__global__ __launch_bounds__(256, 2) void lstm_main(
    const float* __restrict__ x,       // [12][NSEQ]
    const float* __restrict__ WT0,     // [128][512]
    const float* __restrict__ WT1i,    // [128][512]
    const float* __restrict__ WT1h,    // [128][512]
    const float* __restrict__ wih0p,   // [512]
    const float* __restrict__ b0p,     // [512]
    const float* __restrict__ b1p,     // [512]
    const float* __restrict__ fc1_w,   // [32][128]
    const float* __restrict__ fc1_b,   // [32]
    const float* __restrict__ fc2_w,   // [32]
    const float* __restrict__ fc2_b,   // [1]
    float* __restrict__ out)           // [NSEQ]
{
    __shared__ float hT0[HID * HPAD];
    __shared__ float hT1[HID * HPAD];

    const int tid = threadIdx.x;
    const int sg = tid & 7;            // 0..7  -> seqs sg*4..+4
    const int jg = tid >> 3;           // 0..31 -> units jg*4..+4
    const int sg4 = sg * 4;
    const int jbase = jg * 16;
    const int seq0 = blockIdx.x * G;

    for (int i = tid; i < HID * HPAD; i += 256) { hT0[i] = 0.f; hT1[i] = 0.f; }

    float c0[16], c1[16];              // [s*4+u]
    #pragma unroll
    for (int i = 0; i < 16; ++i) { c0[i] = 0.f; c1[i] = 0.f; }
    __syncthreads();

    float a[64];                       // acc [s*16 + u*4 + type]
    float hn[16];                      // [s*4+u]

    for (int t = 0; t < T_STEPS; ++t) {
        // ===== layer 0: a = x*wih0' + b0 + h0 @ WT0 =====
        {
            float4 xv = *(const float4*)&x[t * NSEQ + seq0 + sg4];
            float4 w0  = *(const float4*)(wih0p + jbase + 0);
            float4 w1  = *(const float4*)(wih0p + jbase + 4);
            float4 w2  = *(const float4*)(wih0p + jbase + 8);
            float4 w3  = *(const float4*)(wih0p + jbase + 12);
            float4 bv0 = *(const float4*)(b0p + jbase + 0);
            float4 bv1 = *(const float4*)(b0p + jbase + 4);
            float4 bv2 = *(const float4*)(b0p + jbase + 8);
            float4 bv3 = *(const float4*)(b0p + jbase + 12);
            INIT16(0, xv.x)
            INIT16(1, xv.y)
            INIT16(2, xv.z)
            INIT16(3, xv.w)
        }
        #pragma unroll 2
        for (int k = 0; k < HID; ++k) {
            float4 h4 = *(const float4*)&hT0[k * HPAD + sg4];
            const float* wr = WT0 + k * GATES + jbase;
            float4 w0 = *(const float4*)(wr + 0);
            float4 w1 = *(const float4*)(wr + 4);
            float4 w2 = *(const float4*)(wr + 8);
            float4 w3 = *(const float4*)(wr + 12);
            ROW16(0, h4.x, w0, w1, w2, w3)
            ROW16(1, h4.y, w0, w1, w2, w3)
            ROW16(2, h4.z, w0, w1, w2, w3)
            ROW16(3, h4.w, w0, w1, w2, w3)
        }
        // ===== layer 0 update (pure registers) =====
        #pragma unroll
        for (int s = 0; s < 4; ++s)
            #pragma unroll
            for (int u = 0; u < 4; ++u) {
                float iv = sigf(a[s*16+u*4+0]);
                float fv = sigf(a[s*16+u*4+1]);
                float gv = tanhf(a[s*16+u*4+2]);
                float ov = sigf(a[s*16+u*4+3]);
                float c = fv * c0[s*4+u] + iv * gv;
                c0[s*4+u] = c;
                hn[s*4+u] = ov * tanhf(c);
            }
        __syncthreads();               // all reads of hT0 done
        #pragma unroll
        for (int u = 0; u < 4; ++u)
            *(float4*)&hT0[(jg*4+u) * HPAD + sg4] =
                make_float4(hn[0*4+u], hn[1*4+u], hn[2*4+u], hn[3*4+u]);
        __syncthreads();               // new h0 visible

        // ===== layer 1: a = b1 + h0 @ WT1i + h1 @ WT1h =====
        {
            float4 bv0 = *(const float4*)(b1p + jbase + 0);
            float4 bv1 = *(const float4*)(b1p + jbase + 4);
            float4 bv2 = *(const float4*)(b1p + jbase + 8);
            float4 bv3 = *(const float4*)(b1p + jbase + 12);
            INITB16(0)
            INITB16(1)
            INITB16(2)
            INITB16(3)
        }
        #pragma unroll 2
        for (int k = 0; k < HID; ++k) {
            float4 h04 = *(const float4*)&hT0[k * HPAD + sg4];
            const float* wri = WT1i + k * GATES + jbase;
            float4 w0 = *(const float4*)(wri + 0);
            float4 w1 = *(const float4*)(wri + 4);
            float4 w2 = *(const float4*)(wri + 8);
            float4 w3 = *(const float4*)(wri + 12);
            ROW16(0, h04.x, w0, w1, w2, w3)
            ROW16(1, h04.y, w0, w1, w2, w3)
            ROW16(2, h04.z, w0, w1, w2, w3)
            ROW16(3, h04.w, w0, w1, w2, w3)
            float4 h14 = *(const float4*)&hT1[k * HPAD + sg4];
            const float* wrh = WT1h + k * GATES + jbase;
            float4 v0 = *(const float4*)(wrh + 0);
            float4 v1 = *(const float4*)(wrh + 4);
            float4 v2 = *(const float4*)(wrh + 8);
            float4 v3 = *(const float4*)(wrh + 12);
            ROW16(0, h14.x, v0, v1, v2, v3)
            ROW16(1, h14.y, v0, v1, v2, v3)
            ROW16(2, h14.z, v0, v1, v2, v3)
            ROW16(3, h14.w, v0, v1, v2, v3)
        }
        // ===== layer 1 update =====
        #pragma unroll
        for (int s = 0; s < 4; ++s)
            #pragma unroll
            for (int u = 0; u < 4; ++u) {
                float iv = sigf(a[s*16+u*4+0]);
                float fv = sigf(a[s*16+u*4+1]);
                float gv = tanhf(a[s*16+u*4+2]);
                float ov = sigf(a[s*16+u*4+3]);
                float c = fv * c1[s*4+u] + iv * gv;
                c1[s*4+u] = c;
                hn[s*4+u] = ov * tanhf(c);
            }
        __syncthreads();               // all reads of hT1 done
        #pragma unroll
        for (int u = 0; u < 4; ++u)
            *(float4*)&hT1[(jg*4+u) * HPAD + sg4] =
                make_float4(hn[0*4+u], hn[1*4+u], hn[2*4+u], hn[3*4+u]);
        __syncthreads();               // new h1 visible
    }

    // ===== FC head =====
    float hidv[4];
    #pragma unroll
    for (int r = 0; r < 4; ++r) {
        int task = tid + r * 256;      // 0..1023 = 32 seq x 32 j
        int sL = task & 31, j = task >> 5;
        float ssum = fc1_b[j];
        const float* wrow = fc1_w + j * HID;
        #pragma unroll 8
        for (int k = 0; k < HID; ++k) ssum += hT1[k * HPAD + sL] * wrow[k];
        hidv[r] = fmaxf(ssum, 0.f);
    }
    __syncthreads();
    #pragma unroll
    for (int r = 0; r < 4; ++r) {
        int task = tid + r * 256;
        hT0[(task & 31) * HPAD + (task >> 5)] = hidv[r];   // hid[seq][j]
    }
    __syncthreads();
    if (tid < G) {
        float ssum = fc2_b[0];
        #pragma unroll
        for (int j = 0; j < 32; ++j) ssum += hT0[tid * HPAD + j] * fc2_w[j];
        out[seq0 + tid] = fmaxf(ssum, 0.f);
    }
}

// ---------------------------------------------------------------------------
extern "C" void kernel_launch(void* const* d_in, const int* in_sizes, int n_in,
                              void* d_out, int out_size, void* d_ws, size_t ws_size,
                              hipStream_t stream)
{
    const float* g_data = (const float*)d_in[0];
    const float* weights = (const float*)d_in[1];
    const float* Wih0   = (const float*)d_in[2];
    const float* Whh0   = (const float*)d_in[3];
    const float* bih0   = (const float*)d_in[4];
    const float* bhh0   = (const float*)d_in[5];
    const float* Wih1   = (const float*)d_in[6];
    const float* Whh1   = (const float*)d_in[7];
    const float* bih1   = (const float*)d_in[8];
    const float* bhh1   = (const float*)d_in[9];
    const float* fc1_w  = (const float*)d_in[10];
    const float* fc1_b  = (const float*)d_in[11];
    const float* fc2_w  = (const float*)d_in[12];
    const float* fc2_b  = (const float*)d_in[13];
    float* out = (float*)d_out;

    float* ws     = (float*)d_ws;
    float* x      = ws;                  // 497664
    float* WT0    = x + NSEQ * T_STEPS;  // 65536
    float* WT1i   = WT0 + 65536;         // 65536
    float* WT1h   = WT1i + 65536;        // 65536
    float* wih0p  = WT1h + 65536;        // 512
    float* b0p    = wih0p + 512;         // 512
    float* b1p    = b0p + 512;           // 512

    prep_kernel<<<774, 256, 0, stream>>>(Whh0, Wih1, Whh1, Wih0, bih0, bhh0, bih1, bhh1,
                                         WT0, WT1i, WT1h, wih0p, b0p, b1p);
    income_kernel<<<1944, 256, 0, stream>>>(g_data, weights, x);
    lstm_main<<<NSEQ / G, 256, 0, stream>>>(x, WT0, WT1i, WT1h, wih0p, b0p, b1p,
                                            fc1_w, fc1_b, fc2_w, fc2_b, out);
}

// Round 5
// 2816.589 us; speedup vs baseline: 2.2744x; 1.3243x over previous
//
#include <hip/hip_runtime.h>
#include <math.h>

#define NODES 81
#define B_SZ 512
#define T_STEPS 12
#define NSEQ (B_SZ * NODES)   // 41472
#define HID 128
#define GATES 512
#define SEQB 64               // sequences per block

typedef unsigned short ushort;
typedef __attribute__((ext_vector_type(8))) short short8;
typedef __attribute__((ext_vector_type(4))) float f32x4;

#define MFMA(A, B, C) __builtin_amdgcn_mfma_f32_16x16x32_bf16((A), (B), (C), 0, 0, 0)

__device__ __forceinline__ ushort f2bf(float v) {
    unsigned int u = __float_as_uint(v);
    unsigned int r = (u + 0x7FFFu + ((u >> 16) & 1u)) >> 16;
    return (ushort)r;
}
__device__ __forceinline__ float bf2f(ushort s) {
    return __uint_as_float(((unsigned int)s) << 16);
}
__device__ __forceinline__ float sigf(float v) { return 1.f / (1.f + expf(-v)); }

// ---------------------------------------------------------------------------
// Prep: build MFMA-fragment-major split-bf16 weights.
// Gate permute: n = unit*4 + type (orig j = type*128 + unit).
// Fragment layout per matrix: [ks(4)][nt(32)][sel(2)][lane(64)][j(8)] ushort,
// value = W[k][n] with k = ks*32 + (lane>>4)*8 + j, n = nt*16 + (lane&15).
// sel 0 = bf16 hi, sel 1 = bf16 lo (v - hi).
// ---------------------------------------------------------------------------
__global__ void prep_kernel(const float* __restrict__ Whh0,
                            const float* __restrict__ Wih1,
                            const float* __restrict__ Whh1,
                            const float* __restrict__ Wih0,
                            const float* __restrict__ bih0, const float* __restrict__ bhh0,
                            const float* __restrict__ bih1, const float* __restrict__ bhh1,
                            ushort* __restrict__ WF0,
                            ushort* __restrict__ WF1i,
                            ushort* __restrict__ WF1h,
                            float* __restrict__ wih0p,
                            float* __restrict__ b0p,
                            float* __restrict__ b1p)
{
    int idx = blockIdx.x * 256 + threadIdx.x;   // 394752 total
    if (idx < 393216) {
        int mat = idx >> 17;              // 131072 per matrix
        int li  = idx & 131071;
        int j   = li & 7;
        int l   = (li >> 3) & 63;
        int sel = (li >> 9) & 1;
        int nt  = (li >> 10) & 31;
        int ks  = (li >> 15) & 3;
        int k = ks * 32 + (l >> 4) * 8 + j;
        int n = nt * 16 + (l & 15);
        int jo = (n & 3) * 128 + (n >> 2);       // original gate row
        const float* W = (mat == 0) ? Whh0 : (mat == 1 ? Wih1 : Whh1);
        float v = W[jo * 128 + k];
        ushort hs = f2bf(v);
        ushort ov = sel ? f2bf(v - bf2f(hs)) : hs;
        ushort* D = (mat == 0) ? WF0 : (mat == 1 ? WF1i : WF1h);
        D[li] = ov;
    } else if (idx < 393728) {
        int jp = idx - 393216;
        wih0p[jp] = Wih0[(jp & 3) * 128 + (jp >> 2)];
    } else if (idx < 394240) {
        int jp = idx - 393728;
        int jo = (jp & 3) * 128 + (jp >> 2);
        b0p[jp] = bih0[jo] + bhh0[jo];
    } else if (idx < 394752) {
        int jp = idx - 394240;
        int jo = (jp & 3) * 128 + (jp >> 2);
        b1p[jp] = bih1[jo] + bhh1[jo];
    }
}

// ---------------------------------------------------------------------------
// income = einsum('bta,an->bnt'); stored t-major: x[t][seq], seq = b*81+n
// ---------------------------------------------------------------------------
__global__ void income_kernel(const float* __restrict__ g_data,
                              const float* __restrict__ w,
                              float* __restrict__ x)
{
    int idx = blockIdx.x * 256 + threadIdx.x;   // 497664 exactly
    int n = idx % NODES;
    int r = idx / NODES;
    int t = r % T_STEPS;
    int b = r / T_STEPS;
    const float* grow = g_data + (b * T_STEPS + t) * NODES;
    float s = 0.f;
    #pragma unroll 3
    for (int a = 0; a < NODES; ++a)
        s += grow[a] * w[a * NODES + n];
    x[t * NSEQ + b * NODES + n] = s;
}

// ---------------------------------------------------------------------------
// Fused 2-layer LSTM + FC head on MFMA (split bf16).
// Block = 64 seqs, 512 threads = 8 waves. Wave w: m-tiles {(w>>2)*2, +1},
// n-tiles (w&3)*8 .. +8.  h state in LDS as A-fragment-layout bf16 hi/lo:
// hA[kq(16)][m(64)][j(8)], k = kq*8+j (unit), m = block-local seq.
// ---------------------------------------------------------------------------
__global__ __launch_bounds__(512, 2) void lstm_main(
    const float* __restrict__ x,        // [12][NSEQ]
    const ushort* __restrict__ WF0,     // frag-major split-bf16
    const ushort* __restrict__ WF1i,
    const ushort* __restrict__ WF1h,
    const float* __restrict__ wih0p,    // [512] gate-permuted
    const float* __restrict__ b0p,      // [512]
    const float* __restrict__ b1p,      // [512]
    const float* __restrict__ fc1_w,    // [32][128]
    const float* __restrict__ fc1_b,    // [32]
    const float* __restrict__ fc2_w,    // [32]
    const float* __restrict__ fc2_b,    // [1]
    float* __restrict__ out)            // [NSEQ]
{
    __shared__ __align__(16) unsigned char smem[75008];
    ushort* hA0h = (ushort*)smem;                  // 16 KB  [kq][m][j]
    ushort* hA0l = (ushort*)(smem + 16384);        // 16 KB
    ushort* hA1h = (ushort*)(smem + 32768);        // 16 KB
    ushort* hA1l = (ushort*)(smem + 49152);        // 16 KB
    float*  stg  = (float*)(smem + 65536);         // 8 waves x [16][18] f32
    float*  xs   = (float*)(smem + 74752);         // [64]
    float*  hfc  = (float*)smem;                   // overlay: h1 fp32 [64][128] (last step)
    float*  hidb = (float*)(smem + 65536);         // overlay stg: hid [64][33]

    const int tid = threadIdx.x;
    const int l   = tid & 63;
    const int w   = tid >> 6;
    const int mt0 = (w >> 2) * 2;
    const int ntb = (w & 3) * 8;
    const int seq0 = blockIdx.x * SEQB;

    const int l15 = l & 15;
    const int l16 = l >> 4;
    const int rr  = l16 * 4 + (l & 3);   // row owned after in-quad transpose
    const int q   = l15 >> 2;            // unit-in-tile
    float* stgw = stg + w * 288;

    for (int i = tid; i < 8192; i += 512) {
        hA0h[i] = 0; hA0l[i] = 0; hA1h[i] = 0; hA1l[i] = 0;
    }
    float c0[2][8], c1[2][8];
    #pragma unroll
    for (int mi = 0; mi < 2; ++mi)
        #pragma unroll
        for (int nt = 0; nt < 8; ++nt) { c0[mi][nt] = 0.f; c1[mi][nt] = 0.f; }
    __syncthreads();

    f32x4 acc[2][8];

    for (int t = 0; t < T_STEPS; ++t) {
        if (tid < 64) xs[tid] = x[t * NSEQ + seq0 + tid];

        // ===================== layer 0 matmul: gates = h0 @ W0 =====================
        #pragma unroll
        for (int mi = 0; mi < 2; ++mi)
            #pragma unroll
            for (int nt = 0; nt < 8; ++nt) acc[mi][nt] = (f32x4){0.f, 0.f, 0.f, 0.f};
        #pragma unroll
        for (int ks = 0; ks < 4; ++ks) {
            short8 ah[2], al[2];
            #pragma unroll
            for (int mi = 0; mi < 2; ++mi) {
                int aoff = ((ks * 4 + l16) * 64 + (mt0 + mi) * 16 + l15) * 8;
                ah[mi] = *(const short8*)(hA0h + aoff);
                al[mi] = *(const short8*)(hA0l + aoff);
            }
            #pragma unroll
            for (int nt = 0; nt < 8; ++nt) {
                int fi = (ks * 32 + ntb + nt) * 2;
                short8 bh = *(const short8*)(WF0 + (fi + 0) * 512 + l * 8);
                short8 bl = *(const short8*)(WF0 + (fi + 1) * 512 + l * 8);
                #pragma unroll
                for (int mi = 0; mi < 2; ++mi) {
                    acc[mi][nt] = MFMA(ah[mi], bh, acc[mi][nt]);
                    acc[mi][nt] = MFMA(ah[mi], bl, acc[mi][nt]);
                    acc[mi][nt] = MFMA(al[mi], bh, acc[mi][nt]);
                }
            }
        }
        __syncthreads();   // hA0 reads done; xs visible

        // ===================== layer 0 update =====================
        #pragma unroll
        for (int mi = 0; mi < 2; ++mi) {
            int m = (mt0 + mi) * 16 + rr;
            float xv = xs[m];
            #pragma unroll
            for (int nt = 0; nt < 8; ++nt) {
                f32x4 A = acc[mi][nt];
                #pragma unroll
                for (int r = 0; r < 4; ++r)
                    stgw[(l16 * 4 + r) * 18 + l15] = A[r];
                asm volatile("s_waitcnt lgkmcnt(0)" ::: "memory");
                float gi = stgw[rr * 18 + q * 4 + 0];
                float gf = stgw[rr * 18 + q * 4 + 1];
                float gg = stgw[rr * 18 + q * 4 + 2];
                float go = stgw[rr * 18 + q * 4 + 3];
                asm volatile("s_waitcnt lgkmcnt(0)" ::: "memory");
                int u = (ntb + nt) * 4 + q;
                float4 bv = *(const float4*)(b0p + u * 4);
                float4 wv = *(const float4*)(wih0p + u * 4);
                gi += xv * wv.x + bv.x;
                gf += xv * wv.y + bv.y;
                gg += xv * wv.z + bv.z;
                go += xv * wv.w + bv.w;
                float iv = sigf(gi), fv = sigf(gf), gv = tanhf(gg), ov = sigf(go);
                float c = fv * c0[mi][nt] + iv * gv;
                c0[mi][nt] = c;
                float h = ov * tanhf(c);
                ushort hh = f2bf(h);
                ushort hl = f2bf(h - bf2f(hh));
                int ho = (u >> 3) * 512 + m * 8 + (u & 7);
                hA0h[ho] = hh;
                hA0l[ho] = hl;
            }
        }
        __syncthreads();   // new h0 visible

        // ===================== layer 1 matmul: gates = h0 @ W1i + h1 @ W1h =====================
        #pragma unroll
        for (int mi = 0; mi < 2; ++mi)
            #pragma unroll
            for (int nt = 0; nt < 8; ++nt) acc[mi][nt] = (f32x4){0.f, 0.f, 0.f, 0.f};
        #pragma unroll
        for (int ks = 0; ks < 4; ++ks) {
            short8 ah[2], al[2];
            #pragma unroll
            for (int mi = 0; mi < 2; ++mi) {
                int aoff = ((ks * 4 + l16) * 64 + (mt0 + mi) * 16 + l15) * 8;
                ah[mi] = *(const short8*)(hA0h + aoff);
                al[mi] = *(const short8*)(hA0l + aoff);
            }
            #pragma unroll
            for (int nt = 0; nt < 8; ++nt) {
                int fi = (ks * 32 + ntb + nt) * 2;
                short8 bh = *(const short8*)(WF1i + (fi + 0) * 512 + l * 8);
                short8 bl = *(const short8*)(WF1i + (fi + 1) * 512 + l * 8);
                #pragma unroll
                for (int mi = 0; mi < 2; ++mi) {
                    acc[mi][nt] = MFMA(ah[mi], bh, acc[mi][nt]);
                    acc[mi][nt] = MFMA(ah[mi], bl, acc[mi][nt]);
                    acc[mi][nt] = MFMA(al[mi], bh, acc[mi][nt]);
                }
            }
        }
        #pragma unroll
        for (int ks = 0; ks < 4; ++ks) {
            short8 ah[2], al[2];
            #pragma unroll
            for (int mi = 0; mi < 2; ++mi) {
                int aoff = ((ks * 4 + l16) * 64 + (mt0 + mi) * 16 + l15) * 8;
                ah[mi] = *(const short8*)(hA1h + aoff);
                al[mi] = *(const short8*)(hA1l + aoff);
            }
            #pragma unroll
            for (int nt = 0; nt < 8; ++nt) {
                int fi = (ks * 32 + ntb + nt) * 2;
                short8 bh = *(const short8*)(WF1h + (fi + 0) * 512 + l * 8);
                short8 bl = *(const short8*)(WF1h + (fi + 1) * 512 + l * 8);
                #pragma unroll
                for (int mi = 0; mi < 2; ++mi) {
                    acc[mi][nt] = MFMA(ah[mi], bh, acc[mi][nt]);
                    acc[mi][nt] = MFMA(ah[mi], bl, acc[mi][nt]);
                    acc[mi][nt] = MFMA(al[mi], bh, acc[mi][nt]);
                }
            }
        }
        __syncthreads();   // hA1 (and hA0) reads done

        // ===================== layer 1 update =====================
        #pragma unroll
        for (int mi = 0; mi < 2; ++mi) {
            int m = (mt0 + mi) * 16 + rr;
            #pragma unroll
            for (int nt = 0; nt < 8; ++nt) {
                f32x4 A = acc[mi][nt];
                #pragma unroll
                for (int r = 0; r < 4; ++r)
                    stgw[(l16 * 4 + r) * 18 + l15] = A[r];
                asm volatile("s_waitcnt lgkmcnt(0)" ::: "memory");
                float gi = stgw[rr * 18 + q * 4 + 0];
                float gf = stgw[rr * 18 + q * 4 + 1];
                float gg = stgw[rr * 18 + q * 4 + 2];
                float go = stgw[rr * 18 + q * 4 + 3];
                asm volatile("s_waitcnt lgkmcnt(0)" ::: "memory");
                int u = (ntb + nt) * 4 + q;
                float4 bv = *(const float4*)(b1p + u * 4);
                gi += bv.x; gf += bv.y; gg += bv.z; go += bv.w;
                float iv = sigf(gi), fv = sigf(gf), gv = tanhf(gg), ov = sigf(go);
                float c = fv * c1[mi][nt] + iv * gv;
                c1[mi][nt] = c;
                float h = ov * tanhf(c);
                ushort hh = f2bf(h);
                ushort hl = f2bf(h - bf2f(hh));
                int ho = (u >> 3) * 512 + m * 8 + (u & 7);
                hA1h[ho] = hh;
                hA1l[ho] = hl;
                if (t == T_STEPS - 1) hfc[m * 128 + u] = h;   // fp32 for FC head
            }
        }
        __syncthreads();   // hA1 new visible (hfc for FC phase)
    }

    // ===================== FC head =====================
    {
        int j = tid & 31;
        int sb = (tid >> 5) * 4;
        const float* wrow = fc1_w + j * HID;
        #pragma unroll
        for (int r = 0; r < 4; ++r) {
            int s = sb + r;
            float sum = fc1_b[j];
            #pragma unroll 8
            for (int k = 0; k < HID; ++k) sum += hfc[s * 128 + k] * wrow[k];
            hidb[s * 33 + j] = fmaxf(sum, 0.f);
        }
    }
    __syncthreads();
    if (tid < 64) {
        float sum = fc2_b[0];
        #pragma unroll
        for (int j = 0; j < 32; ++j) sum += hidb[tid * 33 + j] * fc2_w[j];
        out[seq0 + tid] = fmaxf(sum, 0.f);
    }
}

// ---------------------------------------------------------------------------
extern "C" void kernel_launch(void* const* d_in, const int* in_sizes, int n_in,
                              void* d_out, int out_size, void* d_ws, size_t ws_size,
                              hipStream_t stream)
{
    const float* g_data = (const float*)d_in[0];
    const float* weights = (const float*)d_in[1];
    const float* Wih0   = (const float*)d_in[2];
    const float* Whh0   = (const float*)d_in[3];
    const float* bih0   = (const float*)d_in[4];
    const float* bhh0   = (const float*)d_in[5];
    const float* Wih1   = (const float*)d_in[6];
    const float* Whh1   = (const float*)d_in[7];
    const float* bih1   = (const float*)d_in[8];
    const float* bhh1   = (const float*)d_in[9];
    const float* fc1_w  = (const float*)d_in[10];
    const float* fc1_b  = (const float*)d_in[11];
    const float* fc2_w  = (const float*)d_in[12];
    const float* fc2_b  = (const float*)d_in[13];
    float* out = (float*)d_out;

    float* ws = (float*)d_ws;
    float*  x     = ws;                           // 497664 f
    ushort* WF0   = (ushort*)(x + NSEQ * T_STEPS);// 131072 us
    ushort* WF1i  = WF0 + 131072;                 // 131072 us
    ushort* WF1h  = WF1i + 131072;                // 131072 us
    float*  wih0p = (float*)(WF1h + 131072);      // 512 f
    float*  b0p   = wih0p + 512;                  // 512 f
    float*  b1p   = b0p + 512;                    // 512 f

    prep_kernel<<<1542, 256, 0, stream>>>(Whh0, Wih1, Whh1, Wih0, bih0, bhh0, bih1, bhh1,
                                          WF0, WF1i, WF1h, wih0p, b0p, b1p);
    income_kernel<<<1944, 256, 0, stream>>>(g_data, weights, x);
    lstm_main<<<NSEQ / SEQB, 512, 0, stream>>>(x, WF0, WF1i, WF1h, wih0p, b0p, b1p,
                                               fc1_w, fc1_b, fc2_w, fc2_b, out);
}

// Round 6
// 957.418 us; speedup vs baseline: 6.6909x; 2.9419x over previous
//
#include <hip/hip_runtime.h>
#include <math.h>

#define NODES 81
#define B_SZ 512
#define T_STEPS 12
#define NSEQ (B_SZ * NODES)   // 41472
#define HID 128
#define GATES 512
#define SEQB 64               // sequences per block

typedef unsigned short ushort;
typedef unsigned int uint;
typedef __attribute__((ext_vector_type(8))) short short8;
typedef __attribute__((ext_vector_type(4))) float f32x4;

#define MFMA(A, B, C) __builtin_amdgcn_mfma_f32_16x16x32_bf16((A), (B), (C), 0, 0, 0)

__device__ __forceinline__ ushort f2bf(float v) {
    unsigned int u = __float_as_uint(v);
    unsigned int r = (u + 0x7FFFu + ((u >> 16) & 1u)) >> 16;
    return (ushort)r;
}
__device__ __forceinline__ float bf2f(ushort s) {
    return __uint_as_float(((unsigned int)s) << 16);
}
__device__ __forceinline__ float sigf(float v) { return 1.f / (1.f + expf(-v)); }

// ---------------------------------------------------------------------------
// Prep: MFMA-fragment-major split-bf16 weights (layout verified in R4).
// Gate permute: n = unit*4 + type (orig j = type*128 + unit).
// Layout per matrix: [ks(4)][nt(32)][sel(2)][lane(64)][j(8)] ushort,
// value = W[k][n], k = ks*32 + (lane>>4)*8 + j, n = nt*16 + (lane&15).
// ---------------------------------------------------------------------------
__global__ void prep_kernel(const float* __restrict__ Whh0,
                            const float* __restrict__ Wih1,
                            const float* __restrict__ Whh1,
                            const float* __restrict__ Wih0,
                            const float* __restrict__ bih0, const float* __restrict__ bhh0,
                            const float* __restrict__ bih1, const float* __restrict__ bhh1,
                            ushort* __restrict__ WF0,
                            ushort* __restrict__ WF1i,
                            ushort* __restrict__ WF1h,
                            float* __restrict__ wih0p,
                            float* __restrict__ b0p,
                            float* __restrict__ b1p)
{
    int idx = blockIdx.x * 256 + threadIdx.x;   // 394752 total
    if (idx < 393216) {
        int mat = idx >> 17;              // 131072 per matrix
        int li  = idx & 131071;
        int j   = li & 7;
        int l   = (li >> 3) & 63;
        int sel = (li >> 9) & 1;
        int nt  = (li >> 10) & 31;
        int ks  = (li >> 15) & 3;
        int k = ks * 32 + (l >> 4) * 8 + j;
        int n = nt * 16 + (l & 15);
        int jo = (n & 3) * 128 + (n >> 2);       // original gate row
        const float* W = (mat == 0) ? Whh0 : (mat == 1 ? Wih1 : Whh1);
        float v = W[jo * 128 + k];
        ushort hs = f2bf(v);
        ushort ov = sel ? f2bf(v - bf2f(hs)) : hs;
        ushort* D = (mat == 0) ? WF0 : (mat == 1 ? WF1i : WF1h);
        D[li] = ov;
    } else if (idx < 393728) {
        int jp = idx - 393216;
        wih0p[jp] = Wih0[(jp & 3) * 128 + (jp >> 2)];
    } else if (idx < 394240) {
        int jp = idx - 393728;
        int jo = (jp & 3) * 128 + (jp >> 2);
        b0p[jp] = bih0[jo] + bhh0[jo];
    } else if (idx < 394752) {
        int jp = idx - 394240;
        int jo = (jp & 3) * 128 + (jp >> 2);
        b1p[jp] = bih1[jo] + bhh1[jo];
    }
}

// ---------------------------------------------------------------------------
// income = einsum('bta,an->bnt'); stored t-major: x[t][seq], seq = b*81+n
// ---------------------------------------------------------------------------
__global__ void income_kernel(const float* __restrict__ g_data,
                              const float* __restrict__ w,
                              float* __restrict__ x)
{
    int idx = blockIdx.x * 256 + threadIdx.x;   // 497664 exactly
    int n = idx % NODES;
    int r = idx / NODES;
    int t = r % T_STEPS;
    int b = r / T_STEPS;
    const float* grow = g_data + (b * T_STEPS + t) * NODES;
    float s = 0.f;
    #pragma unroll 3
    for (int a = 0; a < NODES; ++a)
        s += grow[a] * w[a * NODES + n];
    x[t * NSEQ + b * NODES + n] = s;
}

// ---------------------------------------------------------------------------
// Fused 2-layer LSTM + FC head on MFMA (split bf16), weight-dedup version.
// Block = 64 seqs, 1024 threads = 16 waves. Wave w owns n-tiles {2w, 2w+1}
// and ALL 4 m-tiles (acc[4] only). h-state double-buffered in LDS as
// A-fragment layout: hA[buf][kq(16)][m(64)][j(8)], k = kq*8+j (unit).
// 2 barriers per step.
// ---------------------------------------------------------------------------
__global__ __launch_bounds__(1024, 1) void lstm_main(
    const float* __restrict__ x,        // [12][NSEQ]
    const ushort* __restrict__ WF0,     // frag-major split-bf16
    const ushort* __restrict__ WF1i,
    const ushort* __restrict__ WF1h,
    const float* __restrict__ wih0p,    // [512] gate-permuted
    const float* __restrict__ b0p,      // [512]
    const float* __restrict__ b1p,      // [512]
    const float* __restrict__ fc1_w,    // [32][128]
    const float* __restrict__ fc1_b,    // [32]
    const float* __restrict__ fc2_w,    // [32]
    const float* __restrict__ fc2_b,    // [1]
    float* __restrict__ out)            // [NSEQ]
{
    __shared__ __align__(16) unsigned char smem[150528];
    ushort* hA0h = (ushort*)smem;                    // [2][8192]
    ushort* hA0l = (ushort*)(smem + 32768);          // [2][8192]
    ushort* hA1h = (ushort*)(smem + 65536);          // [2][8192]
    ushort* hA1l = (ushort*)(smem + 98304);          // [2][8192]
    float*  stg  = (float*)(smem + 131072);          // 16 waves x [16][19] f32

    const int tid = threadIdx.x;
    const int l   = tid & 63;
    const int w   = tid >> 6;            // 0..15
    const int l15 = l & 15;
    const int l16 = l >> 4;
    const int rr  = l16 * 4 + (l & 3);   // row owned after in-group transpose
    const int q   = l15 >> 2;            // unit-in-n-tile
    const int seq0 = blockIdx.x * SEQB;
    float* stgw = stg + w * 304;

    // zero all h-state (both buffers, both layers, hi+lo): 131072 B
    for (int i = tid; i < 32768; i += 1024) ((uint*)smem)[i] = 0u;

    float c0[2][4], c1[2][4];            // [ln][mi]
    #pragma unroll
    for (int a = 0; a < 2; ++a)
        #pragma unroll
        for (int b = 0; b < 4; ++b) { c0[a][b] = 0.f; c1[a][b] = 0.f; }
    __syncthreads();

    f32x4 acc[4];
    int cur = 0;

    for (int t = 0; t < T_STEPS; ++t) {
        const int nxt = cur ^ 1;
        float xv[4];
        #pragma unroll
        for (int mi = 0; mi < 4; ++mi)
            xv[mi] = x[t * NSEQ + seq0 + mi * 16 + rr];

        // =============== layer 0: gates = x*wih0' + b0 + h0 @ W0 ===============
        #pragma unroll
        for (int ln = 0; ln < 2; ++ln) {
            const int nt = w * 2 + ln;
            const int u  = nt * 4 + q;
            float4 wv = *(const float4*)(wih0p + u * 4);
            float4 bv = *(const float4*)(b0p + u * 4);
            #pragma unroll
            for (int mi = 0; mi < 4; ++mi) acc[mi] = (f32x4){0.f, 0.f, 0.f, 0.f};
            #pragma unroll
            for (int ks = 0; ks < 4; ++ks) {
                const int abase = cur * 8192 + ((ks * 4 + l16) * 64 + l15) * 8;
                short8 bh = *(const short8*)(WF0 + ((ks * 32 + nt) * 2 + 0) * 512 + l * 8);
                short8 bl = *(const short8*)(WF0 + ((ks * 32 + nt) * 2 + 1) * 512 + l * 8);
                #pragma unroll
                for (int mi = 0; mi < 4; ++mi) {
                    short8 ah = *(const short8*)(hA0h + abase + mi * 128);
                    short8 al = *(const short8*)(hA0l + abase + mi * 128);
                    acc[mi] = MFMA(ah, bh, acc[mi]);
                    acc[mi] = MFMA(ah, bl, acc[mi]);
                    acc[mi] = MFMA(al, bh, acc[mi]);
                }
            }
            const int kqw = u >> 3, j7 = u & 7;
            #pragma unroll
            for (int mi = 0; mi < 4; ++mi) {
                #pragma unroll
                for (int r = 0; r < 4; ++r)
                    stgw[(l16 * 4 + r) * 19 + l15] = acc[mi][r];
                asm volatile("s_waitcnt lgkmcnt(0)" ::: "memory");
                float gi = stgw[rr * 19 + q * 4 + 0] + xv[mi] * wv.x + bv.x;
                float gf = stgw[rr * 19 + q * 4 + 1] + xv[mi] * wv.y + bv.y;
                float gg = stgw[rr * 19 + q * 4 + 2] + xv[mi] * wv.z + bv.z;
                float go = stgw[rr * 19 + q * 4 + 3] + xv[mi] * wv.w + bv.w;
                asm volatile("s_waitcnt lgkmcnt(0)" ::: "memory");
                float iv = sigf(gi), fv = sigf(gf), gv = tanhf(gg), ov = sigf(go);
                float c = fv * c0[ln][mi] + iv * gv;
                c0[ln][mi] = c;
                float h = ov * tanhf(c);
                ushort hh = f2bf(h), hl = f2bf(h - bf2f(hh));
                int ho = nxt * 8192 + kqw * 512 + (mi * 16 + rr) * 8 + j7;
                hA0h[ho] = hh;
                hA0l[ho] = hl;
            }
        }
        __syncthreads();   // new h0 (buf nxt) visible; all hA0[cur]/hA1 reads for L0 done

        // =============== layer 1: gates = b1 + h0_new @ W1i + h1 @ W1h ===============
        #pragma unroll
        for (int ln = 0; ln < 2; ++ln) {
            const int nt = w * 2 + ln;
            const int u  = nt * 4 + q;
            float4 bv = *(const float4*)(b1p + u * 4);
            #pragma unroll
            for (int mi = 0; mi < 4; ++mi) acc[mi] = (f32x4){0.f, 0.f, 0.f, 0.f};
            #pragma unroll 2
            for (int ks = 0; ks < 4; ++ks) {
                const int ab = ((ks * 4 + l16) * 64 + l15) * 8;
                const int a0 = nxt * 8192 + ab;   // new h0
                const int a1 = cur * 8192 + ab;   // old h1
                short8 bih = *(const short8*)(WF1i + ((ks * 32 + nt) * 2 + 0) * 512 + l * 8);
                short8 bil = *(const short8*)(WF1i + ((ks * 32 + nt) * 2 + 1) * 512 + l * 8);
                short8 bhh = *(const short8*)(WF1h + ((ks * 32 + nt) * 2 + 0) * 512 + l * 8);
                short8 bhl = *(const short8*)(WF1h + ((ks * 32 + nt) * 2 + 1) * 512 + l * 8);
                #pragma unroll
                for (int mi = 0; mi < 4; ++mi) {
                    short8 a0h = *(const short8*)(hA0h + a0 + mi * 128);
                    short8 a0l = *(const short8*)(hA0l + a0 + mi * 128);
                    acc[mi] = MFMA(a0h, bih, acc[mi]);
                    acc[mi] = MFMA(a0h, bil, acc[mi]);
                    acc[mi] = MFMA(a0l, bih, acc[mi]);
                    short8 a1h = *(const short8*)(hA1h + a1 + mi * 128);
                    short8 a1l = *(const short8*)(hA1l + a1 + mi * 128);
                    acc[mi] = MFMA(a1h, bhh, acc[mi]);
                    acc[mi] = MFMA(a1h, bhl, acc[mi]);
                    acc[mi] = MFMA(a1l, bhh, acc[mi]);
                }
            }
            const int kqw = u >> 3, j7 = u & 7;
            #pragma unroll
            for (int mi = 0; mi < 4; ++mi) {
                #pragma unroll
                for (int r = 0; r < 4; ++r)
                    stgw[(l16 * 4 + r) * 19 + l15] = acc[mi][r];
                asm volatile("s_waitcnt lgkmcnt(0)" ::: "memory");
                float gi = stgw[rr * 19 + q * 4 + 0] + bv.x;
                float gf = stgw[rr * 19 + q * 4 + 1] + bv.y;
                float gg = stgw[rr * 19 + q * 4 + 2] + bv.z;
                float go = stgw[rr * 19 + q * 4 + 3] + bv.w;
                asm volatile("s_waitcnt lgkmcnt(0)" ::: "memory");
                float iv = sigf(gi), fv = sigf(gf), gv = tanhf(gg), ov = sigf(go);
                float c = fv * c1[ln][mi] + iv * gv;
                c1[ln][mi] = c;
                float h = ov * tanhf(c);
                ushort hh = f2bf(h), hl = f2bf(h - bf2f(hh));
                int ho = nxt * 8192 + kqw * 512 + (mi * 16 + rr) * 8 + j7;
                hA1h[ho] = hh;
                hA1l[ho] = hl;
            }
        }
        __syncthreads();   // new h1 visible
        cur ^= 1;
    }

    // =============== FC head (h1 reconstructed from split bf16) ===============
    const ushort* Hh = hA1h + cur * 8192;
    const ushort* Hl = hA1l + cur * 8192;
    float* hidb = stg;                   // reuse staging: [64][33]
    float hv2[2];
    #pragma unroll
    for (int r = 0; r < 2; ++r) {
        int task = tid + r * 1024;       // 0..2047 = 64 seq x 32 j
        int s = task >> 5, j = task & 31;
        const float* wrow = fc1_w + j * HID;
        float sum = fc1_b[j];
        #pragma unroll 4
        for (int k = 0; k < HID; ++k) {
            int off = (k >> 3) * 512 + s * 8 + (k & 7);
            float hval = bf2f(Hh[off]) + bf2f(Hl[off]);
            sum += hval * wrow[k];
        }
        hv2[r] = fmaxf(sum, 0.f);
    }
    __syncthreads();                     // staging region free
    #pragma unroll
    for (int r = 0; r < 2; ++r) {
        int task = tid + r * 1024;
        hidb[(task >> 5) * 33 + (task & 31)] = hv2[r];
    }
    __syncthreads();
    if (tid < 64) {
        float sum = fc2_b[0];
        #pragma unroll
        for (int j = 0; j < 32; ++j) sum += hidb[tid * 33 + j] * fc2_w[j];
        out[seq0 + tid] = fmaxf(sum, 0.f);
    }
}

// ---------------------------------------------------------------------------
extern "C" void kernel_launch(void* const* d_in, const int* in_sizes, int n_in,
                              void* d_out, int out_size, void* d_ws, size_t ws_size,
                              hipStream_t stream)
{
    const float* g_data = (const float*)d_in[0];
    const float* weights = (const float*)d_in[1];
    const float* Wih0   = (const float*)d_in[2];
    const float* Whh0   = (const float*)d_in[3];
    const float* bih0   = (const float*)d_in[4];
    const float* bhh0   = (const float*)d_in[5];
    const float* Wih1   = (const float*)d_in[6];
    const float* Whh1   = (const float*)d_in[7];
    const float* bih1   = (const float*)d_in[8];
    const float* bhh1   = (const float*)d_in[9];
    const float* fc1_w  = (const float*)d_in[10];
    const float* fc1_b  = (const float*)d_in[11];
    const float* fc2_w  = (const float*)d_in[12];
    const float* fc2_b  = (const float*)d_in[13];
    float* out = (float*)d_out;

    float* ws = (float*)d_ws;
    float*  x     = ws;                            // 497664 f
    ushort* WF0   = (ushort*)(x + NSEQ * T_STEPS); // 131072 us
    ushort* WF1i  = WF0 + 131072;                  // 131072 us
    ushort* WF1h  = WF1i + 131072;                 // 131072 us
    float*  wih0p = (float*)(WF1h + 131072);       // 512 f
    float*  b0p   = wih0p + 512;                   // 512 f
    float*  b1p   = b0p + 512;                     // 512 f

    prep_kernel<<<1542, 256, 0, stream>>>(Whh0, Wih1, Whh1, Wih0, bih0, bhh0, bih1, bhh1,
                                          WF0, WF1i, WF1h, wih0p, b0p, b1p);
    income_kernel<<<1944, 256, 0, stream>>>(g_data, weights, x);
    lstm_main<<<NSEQ / SEQB, 1024, 0, stream>>>(x, WF0, WF1i, WF1h, wih0p, b0p, b1p,
                                                fc1_w, fc1_b, fc2_w, fc2_b, out);
}